// Round 19
// baseline (282.813 us; speedup 1.0000x reference)
//
#include <hip/hip_runtime.h>
#include <hip/hip_bf16.h>
#include <math.h>

#define DEV __device__ __forceinline__

constexpr int B_ = 4, N_ = 4096, D_ = 512, E_ = 4, H_ = 1024, NF_ = 32;
constexpr int KL_ = 2048, T_ = KL_ + 1;          // 2049
constexpr int TOK_ = B_ * T_;                    // 8196
constexpr int SP_ = 2304;                        // padded rows per sample in xbp

typedef __bf16 bf16x8 __attribute__((ext_vector_type(8)));
typedef float f32x4 __attribute__((ext_vector_type(4)));

// sigmoid-form gelu: x * sigmoid(1.702 x). Max |diff| vs exact-erf gelu ~0.02
DEV float gelu_f(float x){
  float t = __expf(-1.702f * x);
  return x * __builtin_amdgcn_rcpf(1.0f + t);
}
DEV float bf2f(unsigned short u){ union{unsigned int i; float f;} c; c.i = (unsigned)u << 16; return c.f; }
DEV unsigned pack2(float a, float b){
  __hip_bfloat16 ha = __float2bfloat16(a), hb = __float2bfloat16(b);
  unsigned short ua = *(unsigned short*)&ha, ub = *(unsigned short*)&hb;
  return (unsigned)ua | ((unsigned)ub << 16);
}

DEV float wave_sum(float v){
  #pragma unroll
  for (int off = 32; off > 0; off >>= 1) v += __shfl_down(v, off, 64);
  return v;
}

DEV float block_sum256(float v, float* sm){
  v = wave_sum(v);
  int lane = threadIdx.x & 63, wid = threadIdx.x >> 6;
  if (lane == 0) sm[wid] = v;
  __syncthreads();
  if (threadIdx.x == 0) sm[0] = sm[0] + sm[1] + sm[2] + sm[3];
  __syncthreads();
  float r = sm[0];
  __syncthreads();
  return r;
}

// rmsnorm1 + sigmoid score. Writes per-row scalars only.
__global__ void k_rms_score(const float* __restrict__ x, const float* __restrict__ g,
                            const float* __restrict__ aw, const float* __restrict__ ab,
                            float* __restrict__ scores, float* __restrict__ scale){
  __shared__ float sm[4];
  int row = blockIdx.x; int tid = threadIdx.x;
  const float* xr = x + (size_t)row * D_;
  float v0 = xr[tid], v1 = xr[tid + 256];
  float ss = block_sum256(v0 * v0 + v1 * v1, sm);
  float a  = block_sum256(v0 * g[tid] * aw[tid] + v1 * g[tid + 256] * aw[tid + 256], sm);
  float n = fmaxf(sqrtf(ss), 1e-12f);
  float inv = 22.627416997969522f / n;   // sqrt(512)
  float z = inv * a + ab[0];
  float s = 1.0f / (1.0f + expf(-z));
  if (tid == 0){ scores[row] = s; scale[row] = inv * s; }
}

// top-k selection flags via exact rank (ties -> lower index, matches lax.top_k).
__global__ void k_select(const float* __restrict__ scores, int* __restrict__ flags){
  __shared__ float s[N_];
  __shared__ int cnts[4][64];
  int b = blockIdx.y; int tid = threadIdx.x;
  int tile = blockIdx.x * 64;
  const float4* src = (const float4*)(scores + (size_t)b * N_);
  for (int j = tid; j < N_ / 4; j += 256) ((float4*)s)[j] = src[j];
  __syncthreads();
  int tok = tid & 63, part = tid >> 6;
  int i = tile + tok;
  float si = s[i];
  int cnt = 0;
  const float4* sp = (const float4*)(s + part * 1024);
  int jb = part * 1024;
  #pragma unroll 4
  for (int j = 0; j < 256; j++){
    float4 v = sp[j];
    int j4 = jb + j * 4;
    cnt += (v.x > si) || (v.x == si && (j4 + 0) < i);
    cnt += (v.y > si) || (v.y == si && (j4 + 1) < i);
    cnt += (v.z > si) || (v.z == si && (j4 + 2) < i);
    cnt += (v.w > si) || (v.w == si && (j4 + 3) < i);
  }
  cnts[part][tok] = cnt;
  __syncthreads();
  if (tid < 64){
    int c = cnts[0][tid] + cnts[1][tid] + cnts[2][tid] + cnts[3][tid];
    flags[(size_t)b * N_ + tile + tid] = (c < KL_) ? 1 : 0;
  }
}

// compact selected indices ascending.
__global__ void k_compact(const int* __restrict__ flags, int* __restrict__ idx){
  __shared__ int wsum[4];
  int b = blockIdx.x; int tid = threadIdx.x;
  const int* fb = flags + (size_t)b * N_;
  int f[16]; int cnt = 0;
  #pragma unroll
  for (int i = 0; i < 16; i++){ f[i] = fb[tid * 16 + i]; cnt += f[i]; }
  int lane = tid & 63, wid = tid >> 6;
  int v = cnt;
  #pragma unroll
  for (int off = 1; off < 64; off <<= 1){
    int t = __shfl_up(v, off, 64);
    if (lane >= off) v += t;
  }
  if (lane == 63) wsum[wid] = v;
  __syncthreads();
  int base = v - cnt;
  for (int w = 0; w < wid; w++) base += wsum[w];
  int* ib = idx + (size_t)b * KL_;
  #pragma unroll
  for (int i = 0; i < 16; i++){
    if (f[i]) ib[base++] = tid * 16 + i;
  }
}

// shared tail: write xcatb (bf16), rmsnorm2 + gamma2 -> xn2b, gate softmax -> gate.
DEV void rms2_tail(int row, float xc0, float xc1,
                   const float* __restrict__ g2, const float* __restrict__ gw,
                   __hip_bfloat16* __restrict__ xcatb,
                   __hip_bfloat16* __restrict__ xn2b, float* __restrict__ gate,
                   float* sm, float* sg){
  int tid = threadIdx.x;
  __hip_bfloat16* xb = xcatb + (size_t)row * D_;
  xb[tid] = __float2bfloat16(xc0); xb[tid + 256] = __float2bfloat16(xc1);
  float ss = block_sum256(xc0 * xc0 + xc1 * xc1, sm);
  float n = fmaxf(sqrtf(ss), 1e-12f);
  float inv = 22.627416997969522f / n;
  float xn0 = xc0 * inv * g2[tid], xn1 = xc1 * inv * g2[tid + 256];
  __hip_bfloat16* ob = xn2b + (size_t)row * D_;
  ob[tid] = __float2bfloat16(xn0); ob[tid + 256] = __float2bfloat16(xn1);
  const float4* gw4 = (const float4*)gw;
  float4 wa = gw4[tid], wb = gw4[tid + 256];
  float l0 = xn0 * wa.x + xn1 * wb.x, l1 = xn0 * wa.y + xn1 * wb.y;
  float l2 = xn0 * wa.z + xn1 * wb.z, l3 = xn0 * wa.w + xn1 * wb.w;
  l0 = wave_sum(l0); l1 = wave_sum(l1); l2 = wave_sum(l2); l3 = wave_sum(l3);
  int lane = tid & 63, wid = tid >> 6;
  if (lane == 0){ sg[wid*4+0]=l0; sg[wid*4+1]=l1; sg[wid*4+2]=l2; sg[wid*4+3]=l3; }
  __syncthreads();
  if (tid == 0){
    float a0 = sg[0]+sg[4]+sg[8]+sg[12];
    float a1 = sg[1]+sg[5]+sg[9]+sg[13];
    float a2 = sg[2]+sg[6]+sg[10]+sg[14];
    float a3 = sg[3]+sg[7]+sg[11]+sg[15];
    float m = fmaxf(fmaxf(a0, a1), fmaxf(a2, a3));
    float e0 = expf(a0-m), e1 = expf(a1-m), e2 = expf(a2-m), e3 = expf(a3-m);
    float is = 1.f / (e0+e1+e2+e3);
    float* gr = gate + (size_t)row * 4;
    gr[0]=e0*is; gr[1]=e1*is; gr[2]=e2*is; gr[3]=e3*is;
  }
}

// fused gather + rmsnorm2 + gate for the 8192 selected rows. One block per row.
__global__ void k_gatherrms(const float* __restrict__ x, const float* __restrict__ scale,
                            const float* __restrict__ g1, const float* __restrict__ g2,
                            const float* __restrict__ gw, const int* __restrict__ idx,
                            __hip_bfloat16* __restrict__ xcatb,
                            __hip_bfloat16* __restrict__ xn2b, float* __restrict__ gate){
  __shared__ float sm[4];
  __shared__ float sg[16];
  int rid = blockIdx.x;             // [0, B_*KL_)
  int b = rid >> 11, p = rid & (KL_ - 1);
  int tid = threadIdx.x;
  int tok = idx[(size_t)b * KL_ + p];
  float sc = scale[(size_t)b * N_ + tok];
  const float* xr = x + ((size_t)b * N_ + tok) * D_;
  float xc0 = xr[tid] * sc * g1[tid];
  float xc1 = xr[tid + 256] * sc * g1[tid + 256];
  rms2_tail(b * T_ + p, xc0, xc1, g2, gw, xcatb, xn2b, gate, sm, sg);
}

// extra partials: 64-token chunks, 256 blocks total
__global__ void k_extra1(const float* __restrict__ x, const float* __restrict__ scale,
                         const int* __restrict__ flags, float* __restrict__ part){
  int b = blockIdx.y, blk = blockIdx.x;
  int tid = threadIdx.x;
  const int* fb = flags + (size_t)b * N_ + blk * 64;
  const float* sb = scale + (size_t)b * N_ + blk * 64;
  const float2* xp = (const float2*)(x + ((size_t)b * N_ + blk * 64) * D_) + tid;
  float2 acc = {0.f, 0.f};
  for (int i = 0; i < 64; i++){
    if (!fb[i]){
      float s = sb[i];
      float2 v = xp[(size_t)i * 256];
      acc.x += v.x * s; acc.y += v.y * s;
    }
  }
  float* pr = part + ((size_t)(b * 64 + blk)) * D_;
  pr[tid * 2] = acc.x; pr[tid * 2 + 1] = acc.y;
}

// extra row: sum partials + gamma1, then fused rmsnorm2+gate. One block per batch.
__global__ void k_extra2r(const float* __restrict__ part, const float* __restrict__ g1,
                          const float* __restrict__ g2, const float* __restrict__ gw,
                          __hip_bfloat16* __restrict__ xcatb,
                          __hip_bfloat16* __restrict__ xn2b, float* __restrict__ gate){
  __shared__ float sm[4];
  __shared__ float sg[16];
  int b = blockIdx.x; int tid = threadIdx.x;
  float s0 = 0.f, s1 = 0.f;
  for (int i = 0; i < 64; i++){
    const float* pr = part + ((size_t)(b * 64 + i)) * D_;
    s0 += pr[tid]; s1 += pr[tid + 256];
  }
  float xc0 = s0 * g1[tid], xc1 = s1 * g1[tid + 256];
  rms2_tail(b * T_ + KL_, xc0, xc1, g2, gw, xcatb, xn2b, gate, sm, sg);
}

// transpose tile body
DEV void trb_tile(const float* __restrict__ in, __hip_bfloat16* __restrict__ out,
                  int R, int C, int bx, int by){
  __shared__ float t[32][33];
  int c0 = bx * 32, r0 = by * 32;
  int j = threadIdx.x & 31, i4 = threadIdx.x >> 5;
  #pragma unroll
  for (int k = 0; k < 4; k++){
    int i = i4 * 4 + k;
    t[i][j] = in[(size_t)(r0 + i) * C + c0 + j];
  }
  __syncthreads();
  #pragma unroll
  for (int k = 0; k < 4; k++){
    int i = i4 * 4 + k;
    out[(size_t)(c0 + i) * R + r0 + j] = __float2bfloat16(t[j][i]);
  }
}

// merged weight prep: ew1 | ew2 (K-permuted) | proj | conv wpack | 1x1 pack | stats zero.
__global__ void k_wprep(const float* __restrict__ ew1, const float* __restrict__ ew2,
                        const float* __restrict__ proj_w,
                        const float* __restrict__ w39, const float* __restrict__ w19,
                        const float* __restrict__ w9,
                        const float* __restrict__ bott_w, const float* __restrict__ mp_w,
                        __hip_bfloat16* __restrict__ w1b, __hip_bfloat16* __restrict__ w2b,
                        __hip_bfloat16* __restrict__ projb, __hip_bfloat16* __restrict__ wcb,
                        __hip_bfloat16* __restrict__ wb1x1, float* __restrict__ stats){
  int blk = blockIdx.x;
  int tid = threadIdx.x;
  if (blk < 2048){
    int e = blk >> 9, rem = blk & 511;
    int by = rem >> 5, bx = rem & 31;
    trb_tile(ew1 + (size_t)e * D_ * H_, w1b + (size_t)e * D_ * H_, D_, H_, bx, by);
  } else if (blk < 4096){
    int r = blk - 2048;
    int e = r >> 9, r2 = r & 511;
    int bx = r2 & 15, by = r2 >> 4;
    __shared__ float t[32][33];
    const float* ip = ew2 + (size_t)e * H_ * D_;
    __hip_bfloat16* op = w2b + (size_t)e * H_;
    int c0 = bx * 32, r0 = by * 32;
    int j = tid & 31, i4 = tid >> 5;
    #pragma unroll
    for (int k = 0; k < 4; k++){
      int i = i4 * 4 + k;
      t[i][j] = ip[(size_t)(r0 + i) * D_ + c0 + j];
    }
    __syncthreads();
    #pragma unroll
    for (int k = 0; k < 4; k++){
      int i = i4 * 4 + k;
      int v = r0 + j;
      int pv = (v & ~63) | ((v & 15) << 2) | ((v >> 4) & 3);
      op[(size_t)(c0 + i) * 4096 + pv] = __float2bfloat16(t[j][i]);
    }
  } else if (blk < 4160){
    int r = blk - 4096;
    trb_tile(proj_w, projb, 128, D_, r & 15, r >> 4);
  } else if (blk < 4448){
    int i = (blk - 4160) * 256 + tid;
    if (i < 73728){
      const float* w; int KP, KW, base;
      if (i < 40960){ w = w39; KP = 40; KW = 39; base = 0; }
      else if (i < 61440){ w = w19; KP = 20; KW = 19; base = 40960; }
      else { w = w9; KP = 12; KW = 9; base = 61440; }
      int li = i - base;
      int oc = li / (32 * KP);
      int rem = li % (32 * KP);
      int k = rem >> 5, ic = rem & 31;
      float v = (k < KW) ? w[((size_t)oc * 32 + ic) * KW + k] : 0.f;
      wcb[i] = __float2bfloat16(v);
    }
  } else if (blk < 4576){
    int i = (blk - 4448) * 256 + tid;   // [0, 32768): [type][oc][d]
    const float* w = (i < 16384) ? bott_w : mp_w;
    wb1x1[i] = __float2bfloat16(w[i & 16383]);
  } else {
    stats[tid] = 0.f;
  }
}

// bf16 MFMA GEMM, 256x128 tile, 512 threads / 8 waves, PACKED column stores.
template<int EPI>
__launch_bounds__(512)
__global__ void gemm_bt(const __hip_bfloat16* __restrict__ A,
                        const __hip_bfloat16* __restrict__ Bt,
                        __hip_bfloat16* __restrict__ Cb, size_t zstride,
                        int M, int N, int K, int kloc,
                        const float* __restrict__ gatep){
  __shared__ __align__(16) char smem[2][24576];   // [buf][A 16K | B 8K]
  int tid = threadIdx.x;
  unsigned gx = gridDim.x;
  unsigned nwg = gx * gridDim.y;
  unsigned orig = blockIdx.x + gx * blockIdx.y;
  unsigned q = nwg >> 3, r = nwg & 7;
  unsigned xcd = orig & 7, loc = orig >> 3;
  unsigned wg = (xcd < r ? xcd * (q + 1) : r * (q + 1) + (xcd - r) * q) + loc;
  int m0 = (int)(wg / gx) * 256, n0 = (int)(wg % gx) * 128;
  int z = blockIdx.z;
  int koff = z * kloc;
  int ln = tid & 63, wid = tid >> 6;
  int wm = wid >> 1, wn = wid & 1;

  f32x4 acc[4][4] = {};

  auto stage = [&](int buf, int k0){
    #pragma unroll
    for (int c = 0; c < 2; c++){
      int ii = tid + c * 512;
      int rr = ii >> 2, s = ii & 3;
      int gm = m0 + rr; gm = gm < M ? gm : M - 1;
      const __hip_bfloat16* gp = A + (size_t)gm * K + (koff + k0 + ((s ^ (rr & 3)) << 3));
      __builtin_amdgcn_global_load_lds(
          (const __attribute__((address_space(1))) void*)gp,
          (__attribute__((address_space(3))) void*)&smem[buf][ii * 16], 16, 0, 0);
    }
    {
      int ii = tid;
      int rr = ii >> 2, s = ii & 3;
      const __hip_bfloat16* gp = Bt + (size_t)(n0 + rr) * K + (koff + k0 + ((s ^ (rr & 3)) << 3));
      __builtin_amdgcn_global_load_lds(
          (const __attribute__((address_space(1))) void*)gp,
          (__attribute__((address_space(3))) void*)&smem[buf][16384 + ii * 16], 16, 0, 0);
    }
  };

  int nk = kloc >> 5;
  stage(0, 0);
  __syncthreads();
  int slotb = (((ln >> 4) ^ (ln & 3)) << 4);
  for (int t = 0; t < nk; t++){
    int buf = t & 1;
    if (t + 1 < nk) stage(buf ^ 1, (t + 1) << 5);
    bf16x8 af[4], bfr[4];
    #pragma unroll
    for (int m = 0; m < 4; m++){
      int R = wm * 64 + m * 16 + (ln & 15);
      af[m] = *(const bf16x8*)&smem[buf][R * 64 + slotb];
    }
    #pragma unroll
    for (int n = 0; n < 4; n++){
      int R = wn * 64 + n * 16 + (ln & 15);
      bfr[n] = *(const bf16x8*)&smem[buf][16384 + R * 64 + slotb];
    }
    #pragma unroll
    for (int m = 0; m < 4; m++)
      #pragma unroll
      for (int n = 0; n < 4; n++)
        acc[m][n] = __builtin_amdgcn_mfma_f32_16x16x32_bf16(af[m], bfr[n], acc[m][n], 0, 0, 0);
    __syncthreads();
  }

  __hip_bfloat16* Co = Cb + (size_t)z * zstride;
  int e = n0 >> 10;
  int lr = ln & 15;
  #pragma unroll
  for (int m = 0; m < 4; m++){
    int rb = m0 + wm * 64 + m * 16 + ((ln >> 4) << 2);
    float gv[4];
    if (EPI == 1){
      #pragma unroll
      for (int r2 = 0; r2 < 4; r2++)
        gv[r2] = (rb + r2 < M) ? gatep[(size_t)(rb + r2) * 4 + e] : 0.f;
    }
    #pragma unroll
    for (int r2 = 0; r2 < 4; r2++){
      int row = rb + r2;
      if (row < M){
        float v0 = acc[m][0][r2], v1 = acc[m][1][r2];
        float v2 = acc[m][2][r2], v3 = acc[m][3][r2];
        if (EPI == 1){
          v0 = gelu_f(v0) * gv[r2]; v1 = gelu_f(v1) * gv[r2];
          v2 = gelu_f(v2) * gv[r2]; v3 = gelu_f(v3) * gv[r2];
        }
        uint2 pk; pk.x = pack2(v0, v1); pk.y = pack2(v2, v3);
        size_t ci = (size_t)row * N + (n0 + wn * 64 + 4 * lr);
        *(uint2*)&Co[ci] = pk;
      }
    }
  }
}

// MFMA 1x1 conv: 128 tokens x 32 oc per block. type 0: xn2b -> xbp (bf16);
// type 1: maxpool3(xn2b) -> cat[:,96:128] (f32), pool fused into reg-staging.
__global__ __launch_bounds__(256)
void k_1x1M(const __hip_bfloat16* __restrict__ xn2b,
            const __hip_bfloat16* __restrict__ wb1x1,
            __hip_bfloat16* __restrict__ xbp, float* __restrict__ cat){
  __shared__ __align__(16) char smem[2][16384];   // [buf][128 rows][64 bf16]
  int type = blockIdx.y;
  const __hip_bfloat16* W = wb1x1 + (size_t)type * 32 * 512;
  int t0 = blockIdx.x * 128;
  int tid = threadIdx.x, ln = tid & 63, wid = tid >> 6;
  int lr = ln & 15, lg = ln >> 4;

  // type 0: direct global->LDS; type 1: reg-stage with fused maxpool3.
  auto stage = [&](int buf, int k0){
    if (type == 0){
      #pragma unroll
      for (int c = 0; c < 4; c++){
        int ii = tid + c * 256;                 // 1024 16B-slots, 8 per row
        int r = ii >> 3, s = ii & 7;
        int row = t0 + r; row = row < TOK_ ? row : TOK_ - 1;
        const __hip_bfloat16* gp = xn2b + (size_t)row * D_ + k0 + ((s ^ (r & 7)) << 3);
        __builtin_amdgcn_global_load_lds(
            (const __attribute__((address_space(1))) void*)gp,
            (__attribute__((address_space(3))) void*)&smem[buf][ii * 16], 16, 0, 0);
      }
    } else {
      #pragma unroll
      for (int c = 0; c < 4; c++){
        int ii = tid + c * 256;
        int r = ii >> 3, s = ii & 7;
        int g = t0 + r; g = g < TOK_ ? g : TOK_ - 1;
        int t = g % T_;
        const __hip_bfloat16* p = xn2b + (size_t)g * D_ + k0 + ((s ^ (r & 7)) << 3);
        bf16x8 vc = *(const bf16x8*)p;
        float f[8];
        #pragma unroll
        for (int j = 0; j < 8; j++) f[j] = bf2f(((const unsigned short*)&vc)[j]);
        if (t > 0){
          bf16x8 u = *(const bf16x8*)(p - D_);
          #pragma unroll
          for (int j = 0; j < 8; j++) f[j] = fmaxf(f[j], bf2f(((const unsigned short*)&u)[j]));
        }
        if (t < T_ - 1){
          bf16x8 u = *(const bf16x8*)(p + D_);
          #pragma unroll
          for (int j = 0; j < 8; j++) f[j] = fmaxf(f[j], bf2f(((const unsigned short*)&u)[j]));
        }
        uint4 pk;
        pk.x = pack2(f[0], f[1]); pk.y = pack2(f[2], f[3]);
        pk.z = pack2(f[4], f[5]); pk.w = pack2(f[6], f[7]);
        *(uint4*)&smem[buf][ii * 16] = pk;
      }
    }
  };

  f32x4 acc[2][2] = {};
  stage(0, 0);
  __syncthreads();
  for (int t = 0; t < 8; t++){
    int buf = t & 1;
    if (t + 1 < 8) stage(buf ^ 1, (t + 1) * 64);
    int k0 = t * 64;
    #pragma unroll
    for (int kk = 0; kk < 2; kk++){
      bf16x8 bfr[2];
      #pragma unroll
      for (int n = 0; n < 2; n++)
        bfr[n] = *(const bf16x8*)&W[(size_t)(n * 16 + lr) * 512 + k0 + kk * 32 + lg * 8];
      #pragma unroll
      for (int m = 0; m < 2; m++){
        int R = wid * 32 + m * 16 + lr;
        int phys = (kk * 4 + lg) ^ (R & 7);
        bf16x8 af = *(const bf16x8*)&smem[buf][R * 128 + phys * 16];
        acc[m][0] = __builtin_amdgcn_mfma_f32_16x16x32_bf16(af, bfr[0], acc[m][0], 0, 0, 0);
        acc[m][1] = __builtin_amdgcn_mfma_f32_16x16x32_bf16(af, bfr[1], acc[m][1], 0, 0, 0);
      }
    }
    __syncthreads();
  }
  #pragma unroll
  for (int m = 0; m < 2; m++){
    int rb = t0 + wid * 32 + m * 16 + lg * 4;
    #pragma unroll
    for (int n = 0; n < 2; n++){
      int oc = n * 16 + lr;
      #pragma unroll
      for (int r2 = 0; r2 < 4; r2++){
        int g = rb + r2;
        if (g < TOK_){
          float v = acc[m][n][r2];
          if (type == 0){
            int bb = g / T_, t = g % T_;
            xbp[((size_t)(bb * SP_ + 32 + t)) * 32 + oc] = __float2bfloat16(v);
          } else {
            cat[(size_t)g * 128 + 96 + oc] = v;
          }
        }
      }
    }
  }
}

// MFMA implicit-GEMM conv.
template<int KP, int PAD, int OFF, int TYPE>
DEV void convm_body(const __hip_bfloat16* __restrict__ xbp,
                    const __hip_bfloat16* __restrict__ wcb,
                    float* __restrict__ cat, char* smem){
  constexpr int R = KP * 32;
  int t0 = blockIdx.x * 128, b = blockIdx.y;
  int tid = threadIdx.x;
  for (int j = tid; j < 768; j += 256){
    int r = j >> 2, c = j & 3;
    int rg = b * SP_ + 32 + t0 - PAD + r;
    const __hip_bfloat16* gp = xbp + (size_t)rg * 32 + ((c ^ (r & 3)) << 3);
    __builtin_amdgcn_global_load_lds(
        (const __attribute__((address_space(1))) void*)gp,
        (__attribute__((address_space(3))) void*)(smem + j * 16), 16, 0, 0);
  }
  __syncthreads();
  int ln = tid & 63, wid = tid >> 6;
  int lr = ln & 15, lg = ln >> 4;
  int tb = wid * 32;
  const __hip_bfloat16* wt = wcb + OFF;
  const __hip_bfloat16* bp0 = wt + (size_t)lr * R + lg * 8;
  const __hip_bfloat16* bp1 = wt + (size_t)(16 + lr) * R + lg * 8;
  f32x4 acc[2][2] = {};
  bf16x8 bc0 = *(const bf16x8*)bp0;
  bf16x8 bc1 = *(const bf16x8*)bp1;
  #pragma unroll 4
  for (int s = 0; s < KP; s++){
    bf16x8 bn0 = bc0, bn1 = bc1;
    if (s + 1 < KP){
      bn0 = *(const bf16x8*)(bp0 + (s + 1) * 32);
      bn1 = *(const bf16x8*)(bp1 + (s + 1) * 32);
    }
    int ra0 = tb + lr + s;
    int ra1 = tb + 16 + lr + s;
    bf16x8 a0 = *(const bf16x8*)(smem + ra0 * 64 + ((lg ^ (ra0 & 3)) << 4));
    bf16x8 a1 = *(const bf16x8*)(smem + ra1 * 64 + ((lg ^ (ra1 & 3)) << 4));
    acc[0][0] = __builtin_amdgcn_mfma_f32_16x16x32_bf16(a0, bc0, acc[0][0], 0, 0, 0);
    acc[0][1] = __builtin_amdgcn_mfma_f32_16x16x32_bf16(a0, bc1, acc[0][1], 0, 0, 0);
    acc[1][0] = __builtin_amdgcn_mfma_f32_16x16x32_bf16(a1, bc0, acc[1][0], 0, 0, 0);
    acc[1][1] = __builtin_amdgcn_mfma_f32_16x16x32_bf16(a1, bc1, acc[1][1], 0, 0, 0);
    bc0 = bn0; bc1 = bn1;
  }
  #pragma unroll
  for (int m = 0; m < 2; m++){
    int rb = tb + m * 16 + (lg << 2);
    #pragma unroll
    for (int n = 0; n < 2; n++){
      int oc = n * 16 + lr;
      #pragma unroll
      for (int j2 = 0; j2 < 4; j2++){
        int tp = t0 + rb + j2;
        if (tp < T_)
          cat[((size_t)b * T_ + tp) * 128 + TYPE * 32 + oc] = acc[m][n][j2];
      }
    }
  }
}

__global__ __launch_bounds__(256)
void k_convM(const __hip_bfloat16* __restrict__ xbp,
             const __hip_bfloat16* __restrict__ wcb, float* __restrict__ cat){
  __shared__ __align__(16) char smem[192 * 64];
  if (blockIdx.z == 0)      convm_body<40, 19, 0,     0>(xbp, wcb, cat, smem);
  else if (blockIdx.z == 1) convm_body<20, 9,  40960, 1>(xbp, wcb, cat, smem);
  else                      convm_body<12, 4,  61440, 2>(xbp, wcb, cat, smem);
}

// BN stats: coalesced grid-stride, per-channel atomics into stats[0..255]
__global__ void k_bnstat(const float* __restrict__ cat, float* __restrict__ stats){
  __shared__ float sm[512];
  int tid = threadIdx.x;
  float s = 0.f, q = 0.f;
  for (int rp = blockIdx.x; rp < TOK_ / 2; rp += gridDim.x){
    float v = cat[(size_t)rp * 256 + tid];
    s += v; q += v * v;
  }
  sm[tid] = s; sm[256 + tid] = q;
  __syncthreads();
  if (tid < 128){
    atomicAdd(&stats[tid], sm[tid] + sm[tid + 128]);
    atomicAdd(&stats[128 + tid], sm[256 + tid] + sm[256 + tid + 128]);
  }
}

// BN normalize + gelu, output bf16 for the MFMA projection GEMM
__global__ void k_bnact(const float* __restrict__ cat, __hip_bfloat16* __restrict__ catb,
                        const float* __restrict__ stats,
                        const float* __restrict__ g, const float* __restrict__ b){
  int i = blockIdx.x * 256 + threadIdx.x;
  int c = i & 127;
  float mu = stats[c] * (1.f / TOK_);
  float var = stats[128 + c] * (1.f / TOK_) - mu * mu;
  float v = cat[i];
  v = (v - mu) * rsqrtf(var + 1e-5f) * g[c] + b[c];
  catb[i] = __float2bfloat16(gelu_f(v));
}

// out = gelu(xcatb + sum_z moeb[z] + ioutb + pb); block 0 also computes moe_loss.
__global__ void k_final(const __hip_bfloat16* __restrict__ xcatb,
                        const __hip_bfloat16* __restrict__ moeb,
                        size_t zs, const __hip_bfloat16* __restrict__ ioutb,
                        const float* __restrict__ pb, const float* __restrict__ gate,
                        float* __restrict__ out){
  size_t i = ((size_t)blockIdx.x * 256 + threadIdx.x) * 2;
  int p = (int)(i & 511);
  size_t rowbase = i - p;
  float s0 = 0.f, s1 = 0.f;
  #pragma unroll
  for (int z = 0; z < 4; z++){
    unsigned u = *(const unsigned*)&moeb[(size_t)z * zs + i];
    s0 += bf2f((unsigned short)(u & 0xffff));
    s1 += bf2f((unsigned short)(u >> 16));
  }
  unsigned v = *(const unsigned*)&ioutb[i];
  s0 += bf2f((unsigned short)(v & 0xffff));
  s1 += bf2f((unsigned short)(v >> 16));
  int d0 = (p & ~63) | ((p & 3) << 4) | ((p >> 2) & 15);
  int p1 = p + 1;
  int d1 = (p1 & ~63) | ((p1 & 3) << 4) | ((p1 >> 2) & 15);
  const unsigned short* xc = (const unsigned short*)xcatb;
  s0 += bf2f(xc[rowbase + d0]) + pb[d0];
  s1 += bf2f(xc[rowbase + d1]) + pb[d1];
  out[rowbase + d0] = gelu_f(s0);
  out[rowbase + d1] = gelu_f(s1);

  if (blockIdx.x == 0){
    // fused moe_loss: grid-stride over gate, block reduce, single write
    __shared__ float sm[16];
    int tid = threadIdx.x;
    float4 a = {0.f, 0.f, 0.f, 0.f};
    for (int r = tid; r < TOK_; r += 256){
      float4 g4 = *(const float4*)(gate + (size_t)r * 4);
      a.x += g4.x; a.y += g4.y; a.z += g4.z; a.w += g4.w;
    }
    a.x = wave_sum(a.x); a.y = wave_sum(a.y); a.z = wave_sum(a.z); a.w = wave_sum(a.w);
    int lane = tid & 63, wid = tid >> 6;
    if (lane == 0){ sm[wid*4]=a.x; sm[wid*4+1]=a.y; sm[wid*4+2]=a.z; sm[wid*4+3]=a.w; }
    __syncthreads();
    if (tid == 0){
      float l = 0.f;
      #pragma unroll
      for (int e = 0; e < 4; e++){
        float s = sm[e] + sm[4+e] + sm[8+e] + sm[12+e];
        float m = s / (float)TOK_;
        l += m * m;
      }
      out[(size_t)TOK_ * D_] = (float)E_ * l;
    }
  }
}

extern "C" void kernel_launch(void* const* d_in, const int* in_sizes, int n_in,
                              void* d_out, int out_size, void* d_ws, size_t ws_size,
                              hipStream_t stream){
  const float* x      = (const float*)d_in[0];
  const float* gamma1 = (const float*)d_in[2];
  const float* gamma2 = (const float*)d_in[3];
  const float* attn_w = (const float*)d_in[4];
  const float* attn_b = (const float*)d_in[5];
  const float* gate_w = (const float*)d_in[6];
  const float* ew1    = (const float*)d_in[7];
  const float* ew2    = (const float*)d_in[8];
  const float* bott_w = (const float*)d_in[9];
  const float* w39    = (const float*)d_in[10];
  const float* w19    = (const float*)d_in[11];
  const float* w9     = (const float*)d_in[12];
  const float* mp_w   = (const float*)d_in[13];
  const float* bn_g   = (const float*)d_in[14];
  const float* bn_b   = (const float*)d_in[15];
  const float* proj_w = (const float*)d_in[16];
  const float* proj_b = (const float*)d_in[17];
  float* out = (float*)d_out;

  float* ws = (float*)d_ws;
  size_t off = 0;
  auto alloc = [&](size_t n){ size_t o = off; off += (n + 63) & ~(size_t)63; return o; };
  size_t f_hb   = alloc((size_t)TOK_ * 4096 / 2);  // hbuf bf16 TOK x 4096; later ioutb+catb
  size_t f_sc   = alloc(B_ * N_);
  size_t f_sca  = alloc(B_ * N_);
  size_t f_fl   = alloc(B_ * N_);
  size_t f_idx  = alloc(B_ * KL_);
  size_t f_xcb  = alloc((size_t)TOK_ * D_ / 2 + 64);      // xcat bf16 (linear)
  size_t f_moeb = alloc((size_t)4 * TOK_ * D_ / 2 + 64);  // 4 split-K bf16 partials
  size_t f_gate = alloc(TOK_ * E_);
  size_t f_st   = alloc(256);
  size_t f_xbp  = alloc((size_t)B_ * SP_ * 32 / 2);
  size_t f_cat  = alloc((size_t)TOK_ * 128);
  size_t f_wb   = alloc((size_t)(E_ * D_ * H_) + (size_t)TOK_ * D_ / 2 + 64);  // w1b,w2b,xn2b
  size_t f_part = alloc((size_t)B_ * 64 * D_);
  size_t f_wcb  = alloc(73728 / 2 + 64);
  size_t f_pjb  = alloc(512 * 128 / 2 + 64);
  size_t f_w11  = alloc(32768 / 2 + 64);                  // wb1x1 bf16 [2][32][512]
  (void)ws_size; (void)in_sizes; (void)n_in; (void)out_size;

  float* sc   = ws + f_sc;
  float* sca  = ws + f_sca;
  int*   fl   = (int*)(ws + f_fl);
  int*   idx  = (int*)(ws + f_idx);
  float* gate = ws + f_gate;
  float* stats= ws + f_st;
  float* cat  = ws + f_cat;
  float* part = ws + f_part;
  __hip_bfloat16* xcatb = (__hip_bfloat16*)(ws + f_xcb);
  __hip_bfloat16* moeb  = (__hip_bfloat16*)(ws + f_moeb);
  __hip_bfloat16* xbp   = (__hip_bfloat16*)(ws + f_xbp);
  __hip_bfloat16* wcb   = (__hip_bfloat16*)(ws + f_wcb);
  __hip_bfloat16* projb = (__hip_bfloat16*)(ws + f_pjb);
  __hip_bfloat16* wb1x1 = (__hip_bfloat16*)(ws + f_w11);
  __hip_bfloat16* hbuf  = (__hip_bfloat16*)(ws + f_hb);    // TOK x 4096 bf16
  __hip_bfloat16* ioutb = (__hip_bfloat16*)(ws + f_hb);          // TOK x 512 bf16
  __hip_bfloat16* catb  = (__hip_bfloat16*)(ws + f_hb + 4196416); // TOK x 128 bf16
  __hip_bfloat16* w1b  = (__hip_bfloat16*)(ws + f_wb);     // [4096][512] bf16
  __hip_bfloat16* w2b  = w1b + (size_t)E_ * D_ * H_;       // [512][4096] bf16, K-permuted
  __hip_bfloat16* xn2b = w2b + (size_t)E_ * D_ * H_;       // TOK x 512 bf16

  hipMemsetAsync(xbp, 0, (size_t)B_ * SP_ * 32 * sizeof(__hip_bfloat16), stream);

  // merged weight prep + stats zero
  k_wprep<<<4577, 256, 0, stream>>>(ew1, ew2, proj_w, w39, w19, w9, bott_w, mp_w,
                                    w1b, w2b, projb, wcb, wb1x1, stats);

  k_rms_score<<<B_ * N_, 256, 0, stream>>>(x, gamma1, attn_w, attn_b, sc, sca);
  k_select<<<dim3(N_ / 64, B_), 256, 0, stream>>>(sc, fl);
  k_compact<<<B_, 256, 0, stream>>>(fl, idx);
  k_gatherrms<<<B_ * KL_, 256, 0, stream>>>(x, sca, gamma1, gamma2, gate_w, idx,
                                            xcatb, xn2b, gate);
  k_extra1<<<dim3(64, B_), 256, 0, stream>>>(x, sca, fl, part);
  k_extra2r<<<B_, 256, 0, stream>>>(part, gamma1, gamma2, gate_w, xcatb, xn2b, gate);

  int mt = (TOK_ + 255) / 256;   // 33
  size_t zs = (size_t)TOK_ * D_;
  gemm_bt<1><<<dim3(4096/128, mt), 512, 0, stream>>>(
      xn2b, w1b, hbuf, 0, TOK_, 4096, D_, D_, gate);
  gemm_bt<0><<<dim3(D_/128, mt, 4), 512, 0, stream>>>(
      hbuf, w2b, moeb, zs, TOK_, D_, 4096, 1024, nullptr);

  int t128 = (TOK_ + 127) / 128;  // 65
  k_1x1M<<<dim3(t128, 2), 256, 0, stream>>>(xn2b, wb1x1, xbp, cat);
  k_convM<<<dim3(17, 4, 3), 256, 0, stream>>>(xbp, wcb, cat);
  k_bnstat<<<256, 256, 0, stream>>>(cat, stats);
  k_bnact<<<(TOK_ * 128) / 256, 256, 0, stream>>>(cat, catb, stats, bn_g, bn_b);
  gemm_bt<0><<<dim3(D_/128, mt), 512, 0, stream>>>(
      catb, projb, ioutb, 0, TOK_, D_, 128, 128, nullptr);
  k_final<<<((size_t)TOK_ * D_) / 512, 256, 0, stream>>>(xcatb, moeb, zs, ioutb,
                                                         proj_b, gate, out);
}

// Round 20
// 275.685 us; speedup vs baseline: 1.0259x; 1.0259x over previous
//
#include <hip/hip_runtime.h>
#include <hip/hip_bf16.h>
#include <math.h>

#define DEV __device__ __forceinline__

constexpr int B_ = 4, N_ = 4096, D_ = 512, E_ = 4, H_ = 1024, NF_ = 32;
constexpr int KL_ = 2048, T_ = KL_ + 1;          // 2049
constexpr int TOK_ = B_ * T_;                    // 8196
constexpr int SP_ = 2304;                        // padded rows per sample in xbp

typedef __bf16 bf16x8 __attribute__((ext_vector_type(8)));
typedef float f32x4 __attribute__((ext_vector_type(4)));

// sigmoid-form gelu: x * sigmoid(1.702 x). Max |diff| vs exact-erf gelu ~0.02
DEV float gelu_f(float x){
  float t = __expf(-1.702f * x);
  return x * __builtin_amdgcn_rcpf(1.0f + t);
}
DEV float bf2f(unsigned short u){ union{unsigned int i; float f;} c; c.i = (unsigned)u << 16; return c.f; }
DEV unsigned pack2(float a, float b){
  __hip_bfloat16 ha = __float2bfloat16(a), hb = __float2bfloat16(b);
  unsigned short ua = *(unsigned short*)&ha, ub = *(unsigned short*)&hb;
  return (unsigned)ua | ((unsigned)ub << 16);
}

DEV float wave_sum(float v){
  #pragma unroll
  for (int off = 32; off > 0; off >>= 1) v += __shfl_down(v, off, 64);
  return v;
}

DEV float block_sum256(float v, float* sm){
  v = wave_sum(v);
  int lane = threadIdx.x & 63, wid = threadIdx.x >> 6;
  if (lane == 0) sm[wid] = v;
  __syncthreads();
  if (threadIdx.x == 0) sm[0] = sm[0] + sm[1] + sm[2] + sm[3];
  __syncthreads();
  float r = sm[0];
  __syncthreads();
  return r;
}

// rmsnorm1 + sigmoid score. Writes per-row scalars only.
__global__ void k_rms_score(const float* __restrict__ x, const float* __restrict__ g,
                            const float* __restrict__ aw, const float* __restrict__ ab,
                            float* __restrict__ scores, float* __restrict__ scale){
  __shared__ float sm[4];
  int row = blockIdx.x; int tid = threadIdx.x;
  const float* xr = x + (size_t)row * D_;
  float v0 = xr[tid], v1 = xr[tid + 256];
  float ss = block_sum256(v0 * v0 + v1 * v1, sm);
  float a  = block_sum256(v0 * g[tid] * aw[tid] + v1 * g[tid + 256] * aw[tid + 256], sm);
  float n = fmaxf(sqrtf(ss), 1e-12f);
  float inv = 22.627416997969522f / n;   // sqrt(512)
  float z = inv * a + ab[0];
  float s = 1.0f / (1.0f + expf(-z));
  if (tid == 0){ scores[row] = s; scale[row] = inv * s; }
}

// top-k selection flags via exact rank (ties -> lower index, matches lax.top_k).
__global__ void k_select(const float* __restrict__ scores, int* __restrict__ flags){
  __shared__ float s[N_];
  __shared__ int cnts[4][64];
  int b = blockIdx.y; int tid = threadIdx.x;
  int tile = blockIdx.x * 64;
  const float4* src = (const float4*)(scores + (size_t)b * N_);
  for (int j = tid; j < N_ / 4; j += 256) ((float4*)s)[j] = src[j];
  __syncthreads();
  int tok = tid & 63, part = tid >> 6;
  int i = tile + tok;
  float si = s[i];
  int cnt = 0;
  const float4* sp = (const float4*)(s + part * 1024);
  int jb = part * 1024;
  #pragma unroll 4
  for (int j = 0; j < 256; j++){
    float4 v = sp[j];
    int j4 = jb + j * 4;
    cnt += (v.x > si) || (v.x == si && (j4 + 0) < i);
    cnt += (v.y > si) || (v.y == si && (j4 + 1) < i);
    cnt += (v.z > si) || (v.z == si && (j4 + 2) < i);
    cnt += (v.w > si) || (v.w == si && (j4 + 3) < i);
  }
  cnts[part][tok] = cnt;
  __syncthreads();
  if (tid < 64){
    int c = cnts[0][tid] + cnts[1][tid] + cnts[2][tid] + cnts[3][tid];
    flags[(size_t)b * N_ + tile + tid] = (c < KL_) ? 1 : 0;
  }
}

// compact selected indices ascending.
__global__ void k_compact(const int* __restrict__ flags, int* __restrict__ idx){
  __shared__ int wsum[4];
  int b = blockIdx.x; int tid = threadIdx.x;
  const int* fb = flags + (size_t)b * N_;
  int f[16]; int cnt = 0;
  #pragma unroll
  for (int i = 0; i < 16; i++){ f[i] = fb[tid * 16 + i]; cnt += f[i]; }
  int lane = tid & 63, wid = tid >> 6;
  int v = cnt;
  #pragma unroll
  for (int off = 1; off < 64; off <<= 1){
    int t = __shfl_up(v, off, 64);
    if (lane >= off) v += t;
  }
  if (lane == 63) wsum[wid] = v;
  __syncthreads();
  int base = v - cnt;
  for (int w = 0; w < wid; w++) base += wsum[w];
  int* ib = idx + (size_t)b * KL_;
  #pragma unroll
  for (int i = 0; i < 16; i++){
    if (f[i]) ib[base++] = tid * 16 + i;
  }
}

// shared tail: write xcatb (bf16), rmsnorm2 + gamma2 -> xn2b, gate softmax -> gate.
DEV void rms2_tail(int row, float xc0, float xc1,
                   const float* __restrict__ g2, const float* __restrict__ gw,
                   __hip_bfloat16* __restrict__ xcatb,
                   __hip_bfloat16* __restrict__ xn2b, float* __restrict__ gate,
                   float* sm, float* sg){
  int tid = threadIdx.x;
  __hip_bfloat16* xb = xcatb + (size_t)row * D_;
  xb[tid] = __float2bfloat16(xc0); xb[tid + 256] = __float2bfloat16(xc1);
  float ss = block_sum256(xc0 * xc0 + xc1 * xc1, sm);
  float n = fmaxf(sqrtf(ss), 1e-12f);
  float inv = 22.627416997969522f / n;
  float xn0 = xc0 * inv * g2[tid], xn1 = xc1 * inv * g2[tid + 256];
  __hip_bfloat16* ob = xn2b + (size_t)row * D_;
  ob[tid] = __float2bfloat16(xn0); ob[tid + 256] = __float2bfloat16(xn1);
  const float4* gw4 = (const float4*)gw;
  float4 wa = gw4[tid], wb = gw4[tid + 256];
  float l0 = xn0 * wa.x + xn1 * wb.x, l1 = xn0 * wa.y + xn1 * wb.y;
  float l2 = xn0 * wa.z + xn1 * wb.z, l3 = xn0 * wa.w + xn1 * wb.w;
  l0 = wave_sum(l0); l1 = wave_sum(l1); l2 = wave_sum(l2); l3 = wave_sum(l3);
  int lane = tid & 63, wid = tid >> 6;
  if (lane == 0){ sg[wid*4+0]=l0; sg[wid*4+1]=l1; sg[wid*4+2]=l2; sg[wid*4+3]=l3; }
  __syncthreads();
  if (tid == 0){
    float a0 = sg[0]+sg[4]+sg[8]+sg[12];
    float a1 = sg[1]+sg[5]+sg[9]+sg[13];
    float a2 = sg[2]+sg[6]+sg[10]+sg[14];
    float a3 = sg[3]+sg[7]+sg[11]+sg[15];
    float m = fmaxf(fmaxf(a0, a1), fmaxf(a2, a3));
    float e0 = expf(a0-m), e1 = expf(a1-m), e2 = expf(a2-m), e3 = expf(a3-m);
    float is = 1.f / (e0+e1+e2+e3);
    float* gr = gate + (size_t)row * 4;
    gr[0]=e0*is; gr[1]=e1*is; gr[2]=e2*is; gr[3]=e3*is;
  }
}

// fused gather + rmsnorm2 + gate for the 8192 selected rows. One block per row.
__global__ void k_gatherrms(const float* __restrict__ x, const float* __restrict__ scale,
                            const float* __restrict__ g1, const float* __restrict__ g2,
                            const float* __restrict__ gw, const int* __restrict__ idx,
                            __hip_bfloat16* __restrict__ xcatb,
                            __hip_bfloat16* __restrict__ xn2b, float* __restrict__ gate){
  __shared__ float sm[4];
  __shared__ float sg[16];
  int rid = blockIdx.x;             // [0, B_*KL_)
  int b = rid >> 11, p = rid & (KL_ - 1);
  int tid = threadIdx.x;
  int tok = idx[(size_t)b * KL_ + p];
  float sc = scale[(size_t)b * N_ + tok];
  const float* xr = x + ((size_t)b * N_ + tok) * D_;
  float xc0 = xr[tid] * sc * g1[tid];
  float xc1 = xr[tid + 256] * sc * g1[tid + 256];
  rms2_tail(b * T_ + p, xc0, xc1, g2, gw, xcatb, xn2b, gate, sm, sg);
}

// extra partials: 64-token chunks, 256 blocks total
__global__ void k_extra1(const float* __restrict__ x, const float* __restrict__ scale,
                         const int* __restrict__ flags, float* __restrict__ part){
  int b = blockIdx.y, blk = blockIdx.x;
  int tid = threadIdx.x;
  const int* fb = flags + (size_t)b * N_ + blk * 64;
  const float* sb = scale + (size_t)b * N_ + blk * 64;
  const float2* xp = (const float2*)(x + ((size_t)b * N_ + blk * 64) * D_) + tid;
  float2 acc = {0.f, 0.f};
  for (int i = 0; i < 64; i++){
    if (!fb[i]){
      float s = sb[i];
      float2 v = xp[(size_t)i * 256];
      acc.x += v.x * s; acc.y += v.y * s;
    }
  }
  float* pr = part + ((size_t)(b * 64 + blk)) * D_;
  pr[tid * 2] = acc.x; pr[tid * 2 + 1] = acc.y;
}

// extra row: sum partials + gamma1, then fused rmsnorm2+gate. One block per batch.
__global__ void k_extra2r(const float* __restrict__ part, const float* __restrict__ g1,
                          const float* __restrict__ g2, const float* __restrict__ gw,
                          __hip_bfloat16* __restrict__ xcatb,
                          __hip_bfloat16* __restrict__ xn2b, float* __restrict__ gate){
  __shared__ float sm[4];
  __shared__ float sg[16];
  int b = blockIdx.x; int tid = threadIdx.x;
  float s0 = 0.f, s1 = 0.f;
  for (int i = 0; i < 64; i++){
    const float* pr = part + ((size_t)(b * 64 + i)) * D_;
    s0 += pr[tid]; s1 += pr[tid + 256];
  }
  float xc0 = s0 * g1[tid], xc1 = s1 * g1[tid + 256];
  rms2_tail(b * T_ + KL_, xc0, xc1, g2, gw, xcatb, xn2b, gate, sm, sg);
}

// single-block: reduce gate(TOK,4) -> moe_loss
__global__ void k_gsumloss(const float* __restrict__ gate, float* __restrict__ o){
  __shared__ float sm[16];
  int tid = threadIdx.x;
  float4 a = {0.f, 0.f, 0.f, 0.f};
  for (int r = tid; r < TOK_; r += 256){
    float4 v = *(const float4*)(gate + (size_t)r * 4);
    a.x += v.x; a.y += v.y; a.z += v.z; a.w += v.w;
  }
  a.x = wave_sum(a.x); a.y = wave_sum(a.y); a.z = wave_sum(a.z); a.w = wave_sum(a.w);
  int lane = tid & 63, wid = tid >> 6;
  if (lane == 0){ sm[wid*4]=a.x; sm[wid*4+1]=a.y; sm[wid*4+2]=a.z; sm[wid*4+3]=a.w; }
  __syncthreads();
  if (tid == 0){
    float l = 0.f;
    #pragma unroll
    for (int e = 0; e < 4; e++){
      float s = sm[e] + sm[4+e] + sm[8+e] + sm[12+e];
      float m = s / (float)TOK_;
      l += m * m;
    }
    o[0] = (float)E_ * l;
  }
}

// transpose tile body
DEV void trb_tile(const float* __restrict__ in, __hip_bfloat16* __restrict__ out,
                  int R, int C, int bx, int by){
  __shared__ float t[32][33];
  int c0 = bx * 32, r0 = by * 32;
  int j = threadIdx.x & 31, i4 = threadIdx.x >> 5;
  #pragma unroll
  for (int k = 0; k < 4; k++){
    int i = i4 * 4 + k;
    t[i][j] = in[(size_t)(r0 + i) * C + c0 + j];
  }
  __syncthreads();
  #pragma unroll
  for (int k = 0; k < 4; k++){
    int i = i4 * 4 + k;
    out[(size_t)(c0 + i) * R + r0 + j] = __float2bfloat16(t[j][i]);
  }
}

// merged weight prep: ew1 | ew2 (K-permuted) | proj | conv wpack | 1x1 pack | stats zero.
__global__ void k_wprep(const float* __restrict__ ew1, const float* __restrict__ ew2,
                        const float* __restrict__ proj_w,
                        const float* __restrict__ w39, const float* __restrict__ w19,
                        const float* __restrict__ w9,
                        const float* __restrict__ bott_w, const float* __restrict__ mp_w,
                        __hip_bfloat16* __restrict__ w1b, __hip_bfloat16* __restrict__ w2b,
                        __hip_bfloat16* __restrict__ projb, __hip_bfloat16* __restrict__ wcb,
                        __hip_bfloat16* __restrict__ wb1x1, float* __restrict__ stats){
  int blk = blockIdx.x;
  int tid = threadIdx.x;
  if (blk < 2048){
    int e = blk >> 9, rem = blk & 511;
    int by = rem >> 5, bx = rem & 31;
    trb_tile(ew1 + (size_t)e * D_ * H_, w1b + (size_t)e * D_ * H_, D_, H_, bx, by);
  } else if (blk < 4096){
    int r = blk - 2048;
    int e = r >> 9, r2 = r & 511;
    int bx = r2 & 15, by = r2 >> 4;
    __shared__ float t[32][33];
    const float* ip = ew2 + (size_t)e * H_ * D_;
    __hip_bfloat16* op = w2b + (size_t)e * H_;
    int c0 = bx * 32, r0 = by * 32;
    int j = tid & 31, i4 = tid >> 5;
    #pragma unroll
    for (int k = 0; k < 4; k++){
      int i = i4 * 4 + k;
      t[i][j] = ip[(size_t)(r0 + i) * D_ + c0 + j];
    }
    __syncthreads();
    #pragma unroll
    for (int k = 0; k < 4; k++){
      int i = i4 * 4 + k;
      int v = r0 + j;
      int pv = (v & ~63) | ((v & 15) << 2) | ((v >> 4) & 3);
      op[(size_t)(c0 + i) * 4096 + pv] = __float2bfloat16(t[j][i]);
    }
  } else if (blk < 4160){
    int r = blk - 4096;
    trb_tile(proj_w, projb, 128, D_, r & 15, r >> 4);
  } else if (blk < 4448){
    int i = (blk - 4160) * 256 + tid;
    if (i < 73728){
      const float* w; int KP, KW, base;
      if (i < 40960){ w = w39; KP = 40; KW = 39; base = 0; }
      else if (i < 61440){ w = w19; KP = 20; KW = 19; base = 40960; }
      else { w = w9; KP = 12; KW = 9; base = 61440; }
      int li = i - base;
      int oc = li / (32 * KP);
      int rem = li % (32 * KP);
      int k = rem >> 5, ic = rem & 31;
      float v = (k < KW) ? w[((size_t)oc * 32 + ic) * KW + k] : 0.f;
      wcb[i] = __float2bfloat16(v);
    }
  } else if (blk < 4576){
    int i = (blk - 4448) * 256 + tid;   // [0, 32768): [type][oc][d]
    const float* w = (i < 16384) ? bott_w : mp_w;
    wb1x1[i] = __float2bfloat16(w[i & 16383]);
  } else {
    stats[tid] = 0.f;
  }
}

// bf16 MFMA GEMM, 256x128 tile, 512 threads / 8 waves, PACKED column stores.
template<int EPI>
__launch_bounds__(512)
__global__ void gemm_bt(const __hip_bfloat16* __restrict__ A,
                        const __hip_bfloat16* __restrict__ Bt,
                        __hip_bfloat16* __restrict__ Cb, size_t zstride,
                        int M, int N, int K, int kloc,
                        const float* __restrict__ gatep){
  __shared__ __align__(16) char smem[2][24576];   // [buf][A 16K | B 8K]
  int tid = threadIdx.x;
  unsigned gx = gridDim.x;
  unsigned nwg = gx * gridDim.y;
  unsigned orig = blockIdx.x + gx * blockIdx.y;
  unsigned q = nwg >> 3, r = nwg & 7;
  unsigned xcd = orig & 7, loc = orig >> 3;
  unsigned wg = (xcd < r ? xcd * (q + 1) : r * (q + 1) + (xcd - r) * q) + loc;
  int m0 = (int)(wg / gx) * 256, n0 = (int)(wg % gx) * 128;
  int z = blockIdx.z;
  int koff = z * kloc;
  int ln = tid & 63, wid = tid >> 6;
  int wm = wid >> 1, wn = wid & 1;

  f32x4 acc[4][4] = {};

  auto stage = [&](int buf, int k0){
    #pragma unroll
    for (int c = 0; c < 2; c++){
      int ii = tid + c * 512;
      int rr = ii >> 2, s = ii & 3;
      int gm = m0 + rr; gm = gm < M ? gm : M - 1;
      const __hip_bfloat16* gp = A + (size_t)gm * K + (koff + k0 + ((s ^ (rr & 3)) << 3));
      __builtin_amdgcn_global_load_lds(
          (const __attribute__((address_space(1))) void*)gp,
          (__attribute__((address_space(3))) void*)&smem[buf][ii * 16], 16, 0, 0);
    }
    {
      int ii = tid;
      int rr = ii >> 2, s = ii & 3;
      const __hip_bfloat16* gp = Bt + (size_t)(n0 + rr) * K + (koff + k0 + ((s ^ (rr & 3)) << 3));
      __builtin_amdgcn_global_load_lds(
          (const __attribute__((address_space(1))) void*)gp,
          (__attribute__((address_space(3))) void*)&smem[buf][16384 + ii * 16], 16, 0, 0);
    }
  };

  int nk = kloc >> 5;
  stage(0, 0);
  __syncthreads();
  int slotb = (((ln >> 4) ^ (ln & 3)) << 4);
  for (int t = 0; t < nk; t++){
    int buf = t & 1;
    if (t + 1 < nk) stage(buf ^ 1, (t + 1) << 5);
    bf16x8 af[4], bfr[4];
    #pragma unroll
    for (int m = 0; m < 4; m++){
      int R = wm * 64 + m * 16 + (ln & 15);
      af[m] = *(const bf16x8*)&smem[buf][R * 64 + slotb];
    }
    #pragma unroll
    for (int n = 0; n < 4; n++){
      int R = wn * 64 + n * 16 + (ln & 15);
      bfr[n] = *(const bf16x8*)&smem[buf][16384 + R * 64 + slotb];
    }
    #pragma unroll
    for (int m = 0; m < 4; m++)
      #pragma unroll
      for (int n = 0; n < 4; n++)
        acc[m][n] = __builtin_amdgcn_mfma_f32_16x16x32_bf16(af[m], bfr[n], acc[m][n], 0, 0, 0);
    __syncthreads();
  }

  __hip_bfloat16* Co = Cb + (size_t)z * zstride;
  int e = n0 >> 10;
  int lr = ln & 15;
  #pragma unroll
  for (int m = 0; m < 4; m++){
    int rb = m0 + wm * 64 + m * 16 + ((ln >> 4) << 2);
    float gv[4];
    if (EPI == 1){
      #pragma unroll
      for (int r2 = 0; r2 < 4; r2++)
        gv[r2] = (rb + r2 < M) ? gatep[(size_t)(rb + r2) * 4 + e] : 0.f;
    }
    #pragma unroll
    for (int r2 = 0; r2 < 4; r2++){
      int row = rb + r2;
      if (row < M){
        float v0 = acc[m][0][r2], v1 = acc[m][1][r2];
        float v2 = acc[m][2][r2], v3 = acc[m][3][r2];
        if (EPI == 1){
          v0 = gelu_f(v0) * gv[r2]; v1 = gelu_f(v1) * gv[r2];
          v2 = gelu_f(v2) * gv[r2]; v3 = gelu_f(v3) * gv[r2];
        }
        uint2 pk; pk.x = pack2(v0, v1); pk.y = pack2(v2, v3);
        size_t ci = (size_t)row * N + (n0 + wn * 64 + 4 * lr);
        *(uint2*)&Co[ci] = pk;
      }
    }
  }
}

// elementwise maxpool3 over time within each sample: xn2b -> xn2mb (bf16, as uints)
__global__ void k_pool(const unsigned* __restrict__ xin, unsigned* __restrict__ xout){
  size_t i = (size_t)blockIdx.x * 256 + threadIdx.x;   // over TOK_*256 uints
  if (i >= (size_t)TOK_ * 256) return;
  int g = (int)(i >> 8);
  int t = g % T_;
  unsigned c = xin[i];
  float a0 = bf2f((unsigned short)(c & 0xffff)), a1 = bf2f((unsigned short)(c >> 16));
  if (t > 0){
    unsigned u = xin[i - 256];
    a0 = fmaxf(a0, bf2f((unsigned short)(u & 0xffff)));
    a1 = fmaxf(a1, bf2f((unsigned short)(u >> 16)));
  }
  if (t < T_ - 1){
    unsigned u = xin[i + 256];
    a0 = fmaxf(a0, bf2f((unsigned short)(u & 0xffff)));
    a1 = fmaxf(a1, bf2f((unsigned short)(u >> 16)));
  }
  xout[i] = pack2(a0, a1);
}

// MFMA 1x1 conv: 128 tokens x 32 oc per block. type 0: xn2b -> xbp (bf16);
// type 1: xn2mb -> cat[:,96:128] (f32). K=512 in 8 double-buffered 64-wide chunks.
__global__ __launch_bounds__(256)
void k_1x1M(const __hip_bfloat16* __restrict__ xn2b, const __hip_bfloat16* __restrict__ xn2mb,
            const __hip_bfloat16* __restrict__ wb1x1,
            __hip_bfloat16* __restrict__ xbp, float* __restrict__ cat){
  __shared__ __align__(16) char smem[2][16384];   // [buf][128 rows][64 bf16]
  int type = blockIdx.y;
  const __hip_bfloat16* A = type ? xn2mb : xn2b;
  const __hip_bfloat16* W = wb1x1 + (size_t)type * 32 * 512;
  int t0 = blockIdx.x * 128;
  int tid = threadIdx.x, ln = tid & 63, wid = tid >> 6;
  int lr = ln & 15, lg = ln >> 4;

  auto stage = [&](int buf, int k0){
    #pragma unroll
    for (int c = 0; c < 4; c++){
      int ii = tid + c * 256;                 // 1024 16B-slots, 8 per row
      int r = ii >> 3, s = ii & 7;
      int row = t0 + r; row = row < TOK_ ? row : TOK_ - 1;
      const __hip_bfloat16* gp = A + (size_t)row * D_ + k0 + ((s ^ (r & 7)) << 3);
      __builtin_amdgcn_global_load_lds(
          (const __attribute__((address_space(1))) void*)gp,
          (__attribute__((address_space(3))) void*)&smem[buf][ii * 16], 16, 0, 0);
    }
  };

  f32x4 acc[2][2] = {};
  stage(0, 0);
  __syncthreads();
  for (int t = 0; t < 8; t++){
    int buf = t & 1;
    if (t + 1 < 8) stage(buf ^ 1, (t + 1) * 64);
    int k0 = t * 64;
    #pragma unroll
    for (int kk = 0; kk < 2; kk++){
      bf16x8 bfr[2];
      #pragma unroll
      for (int n = 0; n < 2; n++)
        bfr[n] = *(const bf16x8*)&W[(size_t)(n * 16 + lr) * 512 + k0 + kk * 32 + lg * 8];
      #pragma unroll
      for (int m = 0; m < 2; m++){
        int R = wid * 32 + m * 16 + lr;
        int phys = (kk * 4 + lg) ^ (R & 7);
        bf16x8 af = *(const bf16x8*)&smem[buf][R * 128 + phys * 16];
        acc[m][0] = __builtin_amdgcn_mfma_f32_16x16x32_bf16(af, bfr[0], acc[m][0], 0, 0, 0);
        acc[m][1] = __builtin_amdgcn_mfma_f32_16x16x32_bf16(af, bfr[1], acc[m][1], 0, 0, 0);
      }
    }
    __syncthreads();
  }
  #pragma unroll
  for (int m = 0; m < 2; m++){
    int rb = t0 + wid * 32 + m * 16 + lg * 4;
    #pragma unroll
    for (int n = 0; n < 2; n++){
      int oc = n * 16 + lr;
      #pragma unroll
      for (int r2 = 0; r2 < 4; r2++){
        int g = rb + r2;
        if (g < TOK_){
          float v = acc[m][n][r2];
          if (type == 0){
            int bb = g / T_, t = g % T_;
            xbp[((size_t)(bb * SP_ + 32 + t)) * 32 + oc] = __float2bfloat16(v);
          } else {
            cat[(size_t)g * 128 + 96 + oc] = v;
          }
        }
      }
    }
  }
}

// MFMA implicit-GEMM conv.
template<int KP, int PAD, int OFF, int TYPE>
DEV void convm_body(const __hip_bfloat16* __restrict__ xbp,
                    const __hip_bfloat16* __restrict__ wcb,
                    float* __restrict__ cat, char* smem){
  constexpr int R = KP * 32;
  int t0 = blockIdx.x * 128, b = blockIdx.y;
  int tid = threadIdx.x;
  for (int j = tid; j < 768; j += 256){
    int r = j >> 2, c = j & 3;
    int rg = b * SP_ + 32 + t0 - PAD + r;
    const __hip_bfloat16* gp = xbp + (size_t)rg * 32 + ((c ^ (r & 3)) << 3);
    __builtin_amdgcn_global_load_lds(
        (const __attribute__((address_space(1))) void*)gp,
        (__attribute__((address_space(3))) void*)(smem + j * 16), 16, 0, 0);
  }
  __syncthreads();
  int ln = tid & 63, wid = tid >> 6;
  int lr = ln & 15, lg = ln >> 4;
  int tb = wid * 32;
  const __hip_bfloat16* wt = wcb + OFF;
  const __hip_bfloat16* bp0 = wt + (size_t)lr * R + lg * 8;
  const __hip_bfloat16* bp1 = wt + (size_t)(16 + lr) * R + lg * 8;
  f32x4 acc[2][2] = {};
  bf16x8 bc0 = *(const bf16x8*)bp0;
  bf16x8 bc1 = *(const bf16x8*)bp1;
  #pragma unroll 4
  for (int s = 0; s < KP; s++){
    bf16x8 bn0 = bc0, bn1 = bc1;
    if (s + 1 < KP){
      bn0 = *(const bf16x8*)(bp0 + (s + 1) * 32);
      bn1 = *(const bf16x8*)(bp1 + (s + 1) * 32);
    }
    int ra0 = tb + lr + s;
    int ra1 = tb + 16 + lr + s;
    bf16x8 a0 = *(const bf16x8*)(smem + ra0 * 64 + ((lg ^ (ra0 & 3)) << 4));
    bf16x8 a1 = *(const bf16x8*)(smem + ra1 * 64 + ((lg ^ (ra1 & 3)) << 4));
    acc[0][0] = __builtin_amdgcn_mfma_f32_16x16x32_bf16(a0, bc0, acc[0][0], 0, 0, 0);
    acc[0][1] = __builtin_amdgcn_mfma_f32_16x16x32_bf16(a0, bc1, acc[0][1], 0, 0, 0);
    acc[1][0] = __builtin_amdgcn_mfma_f32_16x16x32_bf16(a1, bc0, acc[1][0], 0, 0, 0);
    acc[1][1] = __builtin_amdgcn_mfma_f32_16x16x32_bf16(a1, bc1, acc[1][1], 0, 0, 0);
    bc0 = bn0; bc1 = bn1;
  }
  #pragma unroll
  for (int m = 0; m < 2; m++){
    int rb = tb + m * 16 + (lg << 2);
    #pragma unroll
    for (int n = 0; n < 2; n++){
      int oc = n * 16 + lr;
      #pragma unroll
      for (int j2 = 0; j2 < 4; j2++){
        int tp = t0 + rb + j2;
        if (tp < T_)
          cat[((size_t)b * T_ + tp) * 128 + TYPE * 32 + oc] = acc[m][n][j2];
      }
    }
  }
}

__global__ __launch_bounds__(256)
void k_convM(const __hip_bfloat16* __restrict__ xbp,
             const __hip_bfloat16* __restrict__ wcb, float* __restrict__ cat){
  __shared__ __align__(16) char smem[192 * 64];
  if (blockIdx.z == 0)      convm_body<40, 19, 0,     0>(xbp, wcb, cat, smem);
  else if (blockIdx.z == 1) convm_body<20, 9,  40960, 1>(xbp, wcb, cat, smem);
  else                      convm_body<12, 4,  61440, 2>(xbp, wcb, cat, smem);
}

// BN stats: coalesced grid-stride, per-channel atomics into stats[0..255]
__global__ void k_bnstat(const float* __restrict__ cat, float* __restrict__ stats){
  __shared__ float sm[512];
  int tid = threadIdx.x;
  float s = 0.f, q = 0.f;
  for (int rp = blockIdx.x; rp < TOK_ / 2; rp += gridDim.x){
    float v = cat[(size_t)rp * 256 + tid];
    s += v; q += v * v;
  }
  sm[tid] = s; sm[256 + tid] = q;
  __syncthreads();
  if (tid < 128){
    atomicAdd(&stats[tid], sm[tid] + sm[tid + 128]);
    atomicAdd(&stats[128 + tid], sm[256 + tid] + sm[256 + tid + 128]);
  }
}

// BN normalize + gelu, output bf16 for the MFMA projection GEMM
__global__ void k_bnact(const float* __restrict__ cat, __hip_bfloat16* __restrict__ catb,
                        const float* __restrict__ stats,
                        const float* __restrict__ g, const float* __restrict__ b){
  int i = blockIdx.x * 256 + threadIdx.x;
  int c = i & 127;
  float mu = stats[c] * (1.f / TOK_);
  float var = stats[128 + c] * (1.f / TOK_) - mu * mu;
  float v = cat[i];
  v = (v - mu) * rsqrtf(var + 1e-5f) * g[c] + b[c];
  catb[i] = __float2bfloat16(gelu_f(v));
}

// out = gelu(xcatb + sum_z moeb[z] + ioutb + pb). moeb/ioutb col-PACKED.
__global__ void k_final(const __hip_bfloat16* __restrict__ xcatb,
                        const __hip_bfloat16* __restrict__ moeb,
                        size_t zs, const __hip_bfloat16* __restrict__ ioutb,
                        const float* __restrict__ pb, float* __restrict__ out){
  size_t i = ((size_t)blockIdx.x * 256 + threadIdx.x) * 2;
  int p = (int)(i & 511);
  size_t rowbase = i - p;
  float s0 = 0.f, s1 = 0.f;
  #pragma unroll
  for (int z = 0; z < 4; z++){
    unsigned u = *(const unsigned*)&moeb[(size_t)z * zs + i];
    s0 += bf2f((unsigned short)(u & 0xffff));
    s1 += bf2f((unsigned short)(u >> 16));
  }
  unsigned v = *(const unsigned*)&ioutb[i];
  s0 += bf2f((unsigned short)(v & 0xffff));
  s1 += bf2f((unsigned short)(v >> 16));
  int d0 = (p & ~63) | ((p & 3) << 4) | ((p >> 2) & 15);
  int p1 = p + 1;
  int d1 = (p1 & ~63) | ((p1 & 3) << 4) | ((p1 >> 2) & 15);
  const unsigned short* xc = (const unsigned short*)xcatb;
  s0 += bf2f(xc[rowbase + d0]) + pb[d0];
  s1 += bf2f(xc[rowbase + d1]) + pb[d1];
  out[rowbase + d0] = gelu_f(s0);
  out[rowbase + d1] = gelu_f(s1);
}

extern "C" void kernel_launch(void* const* d_in, const int* in_sizes, int n_in,
                              void* d_out, int out_size, void* d_ws, size_t ws_size,
                              hipStream_t stream){
  const float* x      = (const float*)d_in[0];
  const float* gamma1 = (const float*)d_in[2];
  const float* gamma2 = (const float*)d_in[3];
  const float* attn_w = (const float*)d_in[4];
  const float* attn_b = (const float*)d_in[5];
  const float* gate_w = (const float*)d_in[6];
  const float* ew1    = (const float*)d_in[7];
  const float* ew2    = (const float*)d_in[8];
  const float* bott_w = (const float*)d_in[9];
  const float* w39    = (const float*)d_in[10];
  const float* w19    = (const float*)d_in[11];
  const float* w9     = (const float*)d_in[12];
  const float* mp_w   = (const float*)d_in[13];
  const float* bn_g   = (const float*)d_in[14];
  const float* bn_b   = (const float*)d_in[15];
  const float* proj_w = (const float*)d_in[16];
  const float* proj_b = (const float*)d_in[17];
  float* out = (float*)d_out;

  float* ws = (float*)d_ws;
  size_t off = 0;
  auto alloc = [&](size_t n){ size_t o = off; off += (n + 63) & ~(size_t)63; return o; };
  size_t f_hb   = alloc((size_t)TOK_ * 4096 / 2);  // hbuf bf16 TOK x 4096; later ioutb+catb
  size_t f_sc   = alloc(B_ * N_);
  size_t f_sca  = alloc(B_ * N_);
  size_t f_fl   = alloc(B_ * N_);
  size_t f_idx  = alloc(B_ * KL_);
  size_t f_xcb  = alloc((size_t)TOK_ * D_ / 2 + 64);      // xcat bf16 (linear)
  size_t f_moeb = alloc((size_t)4 * TOK_ * D_ / 2 + 64);  // 4 split-K bf16 partials
  size_t f_gate = alloc(TOK_ * E_);
  size_t f_st   = alloc(256);
  size_t f_xbp  = alloc((size_t)B_ * SP_ * 32 / 2);
  size_t f_xmb  = alloc((size_t)TOK_ * D_ / 2 + 64);      // maxpooled xn2 bf16
  size_t f_cat  = alloc((size_t)TOK_ * 128);
  size_t f_wb   = alloc((size_t)(E_ * D_ * H_) + (size_t)TOK_ * D_ / 2 + 64);  // w1b,w2b,xn2b
  size_t f_part = alloc((size_t)B_ * 64 * D_);
  size_t f_wcb  = alloc(73728 / 2 + 64);
  size_t f_pjb  = alloc(512 * 128 / 2 + 64);
  size_t f_w11  = alloc(32768 / 2 + 64);                  // wb1x1 bf16 [2][32][512]
  (void)ws_size; (void)in_sizes; (void)n_in; (void)out_size;

  float* sc   = ws + f_sc;
  float* sca  = ws + f_sca;
  int*   fl   = (int*)(ws + f_fl);
  int*   idx  = (int*)(ws + f_idx);
  float* gate = ws + f_gate;
  float* stats= ws + f_st;
  float* cat  = ws + f_cat;
  float* part = ws + f_part;
  __hip_bfloat16* xcatb = (__hip_bfloat16*)(ws + f_xcb);
  __hip_bfloat16* moeb  = (__hip_bfloat16*)(ws + f_moeb);
  __hip_bfloat16* xbp   = (__hip_bfloat16*)(ws + f_xbp);
  __hip_bfloat16* xn2mb = (__hip_bfloat16*)(ws + f_xmb);
  __hip_bfloat16* wcb   = (__hip_bfloat16*)(ws + f_wcb);
  __hip_bfloat16* projb = (__hip_bfloat16*)(ws + f_pjb);
  __hip_bfloat16* wb1x1 = (__hip_bfloat16*)(ws + f_w11);
  __hip_bfloat16* hbuf  = (__hip_bfloat16*)(ws + f_hb);    // TOK x 4096 bf16
  __hip_bfloat16* ioutb = (__hip_bfloat16*)(ws + f_hb);          // TOK x 512 bf16
  __hip_bfloat16* catb  = (__hip_bfloat16*)(ws + f_hb + 4196416); // TOK x 128 bf16
  __hip_bfloat16* w1b  = (__hip_bfloat16*)(ws + f_wb);     // [4096][512] bf16
  __hip_bfloat16* w2b  = w1b + (size_t)E_ * D_ * H_;       // [512][4096] bf16, K-permuted
  __hip_bfloat16* xn2b = w2b + (size_t)E_ * D_ * H_;       // TOK x 512 bf16

  hipMemsetAsync(xbp, 0, (size_t)B_ * SP_ * 32 * sizeof(__hip_bfloat16), stream);

  // merged weight prep + stats zero
  k_wprep<<<4577, 256, 0, stream>>>(ew1, ew2, proj_w, w39, w19, w9, bott_w, mp_w,
                                    w1b, w2b, projb, wcb, wb1x1, stats);

  k_rms_score<<<B_ * N_, 256, 0, stream>>>(x, gamma1, attn_w, attn_b, sc, sca);
  k_select<<<dim3(N_ / 64, B_), 256, 0, stream>>>(sc, fl);
  k_compact<<<B_, 256, 0, stream>>>(fl, idx);
  k_gatherrms<<<B_ * KL_, 256, 0, stream>>>(x, sca, gamma1, gamma2, gate_w, idx,
                                            xcatb, xn2b, gate);
  k_extra1<<<dim3(64, B_), 256, 0, stream>>>(x, sca, fl, part);
  k_extra2r<<<B_, 256, 0, stream>>>(part, gamma1, gamma2, gate_w, xcatb, xn2b, gate);
  k_gsumloss<<<1, 256, 0, stream>>>(gate, out + (size_t)TOK_ * D_);

  int mt = (TOK_ + 255) / 256;   // 33
  size_t zs = (size_t)TOK_ * D_;
  gemm_bt<1><<<dim3(4096/128, mt), 512, 0, stream>>>(
      xn2b, w1b, hbuf, 0, TOK_, 4096, D_, D_, gate);
  gemm_bt<0><<<dim3(D_/128, mt, 4), 512, 0, stream>>>(
      hbuf, w2b, moeb, zs, TOK_, D_, 4096, 1024, nullptr);

  int t128 = (TOK_ + 127) / 128;  // 65
  k_pool<<<(TOK_ * 256 + 255) / 256, 256, 0, stream>>>((const unsigned*)xn2b, (unsigned*)xn2mb);
  k_1x1M<<<dim3(t128, 2), 256, 0, stream>>>(xn2b, xn2mb, wb1x1, xbp, cat);
  k_convM<<<dim3(17, 4, 3), 256, 0, stream>>>(xbp, wcb, cat);
  k_bnstat<<<256, 256, 0, stream>>>(cat, stats);
  k_bnact<<<(TOK_ * 128) / 256, 256, 0, stream>>>(cat, catb, stats, bn_g, bn_b);
  gemm_bt<0><<<dim3(D_/128, mt), 512, 0, stream>>>(
      catb, projb, ioutb, 0, TOK_, D_, 128, 128, nullptr);
  k_final<<<((size_t)TOK_ * D_) / 512, 256, 0, stream>>>(xcatb, moeb, zs, ioutb,
                                                         proj_b, out);
}